// Round 4
// baseline (5434.406 us; speedup 1.0000x reference)
//
#include <hip/hip_runtime.h>
#include <stdint.h>

#define NB 64
#define NS 512
#define NI 512
#define NH 512

typedef __attribute__((ext_vector_type(8))) short bf16x8;
typedef __attribute__((ext_vector_type(4))) float f32x4;

__device__ __forceinline__ unsigned short f2bf(float f) {
  unsigned u = __float_as_uint(f);
  return (unsigned short)((u + 0x7fffu + ((u >> 16) & 1u)) >> 16);
}
__device__ __forceinline__ float bf2f(unsigned short h) {
  return __uint_as_float(((unsigned)h) << 16);
}
__device__ __forceinline__ float sigm(float x) { return 1.0f / (1.0f + __expf(-x)); }
__device__ __forceinline__ float tanh_f(float x) {
  float e = __expf(-2.0f * fabsf(x));
  return copysignf((1.0f - e) / (1.0f + e), x);
}

// ws layout (u32 units):
//  [0,512):              flags[4 m-groups][128], idx = n*2 + half; monotonic step counters
//  [1024, 1024+65536):   h_ex[2 bufs][64 b][512 j]  (packed bf16 hi | lo<<16)
//  [66560, +8388608):    x_bf16 as u16[64][512][512]
#define FLAGS_OFF 0
#define HEX_OFF 1024
#define XBF_OFF 66560
#define WS_BYTES_NEEDED (XBF_OFF * 4 + (size_t)NB * NS * NI * 2)

__global__ __launch_bounds__(256) void k_xconv(const float* __restrict__ x,
                                               unsigned short* __restrict__ xb) {
  size_t i = ((size_t)blockIdx.x * 256 + threadIdx.x) * 4;
  float4 v = *(const float4*)(x + i);
  ushort4 o;
  o.x = f2bf(v.x); o.y = f2bf(v.y); o.z = f2bf(v.z); o.w = f2bf(v.w);
  *(ushort4*)(xb + i) = o;
}

__global__ __launch_bounds__(256) void k_init(const float* __restrict__ h0,
                                              unsigned int* __restrict__ ws) {
  int idx = blockIdx.x * 256 + threadIdx.x;
  if (idx < NB * NH) {
    float v = h0[idx];
    unsigned short hi = f2bf(v);
    unsigned short lo = f2bf(v - bf2f(hi));
    ws[HEX_OFF + idx] = (unsigned)hi | ((unsigned)lo << 16);
  }
  if (idx < 512) ws[FLAGS_OFF + idx] = 1u;  // h version 0 available
}

// Persistent cooperative LSTM kernel.
// grid 256 WGs x 512 thr. WG: m=bid&3 (16 batches), n=bid>>2 (8 h-cols -> 32 gate rows).
// wave w: half=w>>2 selects 16-gate-row half (4 h-cols), kw=w&3 selects K-quarter.
// NO fences anywhere: producers publish h via relaxed agent-scope (sc1,
// MALL-coherent) stores + vmcnt(0) + flag; 2 loader waves (6,7) poll 64 half-
// flags each and stage 16KB each via coalesced agent-scope u64 atomic loads ->
// XOR-swizzled LDS (conflict-free b128 fragment reads). L1/L2 never invalidated.
__global__ __launch_bounds__(512, 2) void k_lstm(
    const float* __restrict__ Wih, const float* __restrict__ bih,
    const float* __restrict__ Whh, const float* __restrict__ bhh,
    const float* __restrict__ c0, float* __restrict__ out,
    unsigned int* __restrict__ ws) {
  const int tid = threadIdx.x;
  const int lane = tid & 63;
  const int w = tid >> 6;
  const int half = w >> 2;
  const int kw = w & 3;
  const int k0 = kw * 128;
  const int m = blockIdx.x & 3;
  const int n = blockIdx.x >> 2;

  unsigned int* flags = ws + FLAGS_OFF + m * 128;
  unsigned int* hex = ws + HEX_OFF;
  const unsigned short* xb = (const unsigned short*)(ws + XBF_OFF);

  // B-fragment lane mapping: col=lane&15, k=(lane>>4)*8+r
  const int c = lane & 15;
  const int q = lane >> 4;
  const int jj = c & 3;
  const int gate = c >> 2;
  const int wrow = gate * NH + n * 8 + half * 4 + jj;  // this wave's gate rows

  // ---- stage weight fragments into registers (hi/lo bf16 split) ----
  bf16x8 whh_hi[4], whh_lo[4], wih_hi[4], wih_lo[4];
#pragma unroll
  for (int kc = 0; kc < 4; ++kc) {
    int kb = k0 + kc * 32 + q * 8;
    const float* ph = Whh + (size_t)wrow * NH + kb;
    const float* pi = Wih + (size_t)wrow * NI + kb;
    float4 a0 = *(const float4*)ph, a1 = *(const float4*)(ph + 4);
    float4 b0 = *(const float4*)pi, b1 = *(const float4*)(pi + 4);
    float vh[8] = {a0.x, a0.y, a0.z, a0.w, a1.x, a1.y, a1.z, a1.w};
    float vi[8] = {b0.x, b0.y, b0.z, b0.w, b1.x, b1.y, b1.z, b1.w};
#pragma unroll
    for (int r = 0; r < 8; ++r) {
      unsigned short h16 = f2bf(vh[r]);
      whh_hi[kc][r] = (short)h16;
      whh_lo[kc][r] = (short)f2bf(vh[r] - bf2f(h16));
      unsigned short i16 = f2bf(vi[r]);
      wih_hi[kc][r] = (short)i16;
      wih_lo[kc][r] = (short)f2bf(vi[r] - bf2f(i16));
    }
  }

  const float biasr = bih[wrow] + bhh[wrow];

  // epilogue state (reducer waves 0,4): lane = (b=lane&15, j2=lane>>4)
  const int eb = m * 16 + (lane & 15);
  const int j2 = lane >> 4;
  const int jg = n * 8 + half * 4 + j2;
  float cst = c0[(size_t)eb * NH + jg];

  // LDS: XOR-swizzled h block (u32 idx: b*512 + (j ^ ((b&7)<<2))), partials, gates
  __shared__ unsigned LhexF[16 * 512];
  __shared__ float part[6][4][64];  // slots: w1,2,3 -> 0,1,2; w5,6,7 -> 3,4,5
  __shared__ float gl[2][16][17];

  const unsigned short* xbase = xb + (size_t)eb * NS * NI + k0 + q * 8;

  for (int t = 0; t < NS; ++t) {
    // issue x loads early (in flight during poll/stage; consumed after S1)
    bf16x8 xf[4];
    const unsigned short* xr = xbase + (size_t)t * NI;
#pragma unroll
    for (int kc = 0; kc < 4; ++kc) xf[kc] = *(const bf16x8*)(xr + kc * 32);

    if (w >= 6) {
      const int lh = w - 6;  // stages u32 cols [lh*256, lh*256+256)
      unsigned tgt = (unsigned)(t + 1);
      const unsigned* fp = flags + lh * 64 + lane;  // flags for n = lh*32..+31
      unsigned fl = __hip_atomic_load(fp, __ATOMIC_RELAXED, __HIP_MEMORY_SCOPE_AGENT);
      while (!__all((int)(fl >= tgt)))
        fl = __hip_atomic_load(fp, __ATOMIC_RELAXED, __HIP_MEMORY_SCOPE_AGENT);
      asm volatile("" ::: "memory");  // keep hex loads below the poll

      const unsigned long long* src =
          (const unsigned long long*)(hex + (size_t)(t & 1) * (NB * NH) + (size_t)m * 16 * NH) +
          lh * 128 + 2 * lane;
      const unsigned lbase = (unsigned)(lh * 256 + 4 * lane);
#pragma unroll
      for (int b = 0; b < 16; ++b) {
        unsigned long long d0 = __hip_atomic_load(src + (size_t)b * 256,
                                                  __ATOMIC_RELAXED, __HIP_MEMORY_SCOPE_AGENT);
        unsigned long long d1 = __hip_atomic_load(src + (size_t)b * 256 + 1,
                                                  __ATOMIC_RELAXED, __HIP_MEMORY_SCOPE_AGENT);
        unsigned p = b * 512 + (lbase ^ ((unsigned)(b & 7) << 2));
        uint4 v;
        v.x = (unsigned)d0; v.y = (unsigned)(d0 >> 32);
        v.z = (unsigned)d1; v.w = (unsigned)(d1 >> 32);
        *(uint4*)&LhexF[p] = v;
      }
    }
    __syncthreads();  // S1: staging visible

    // x-path MFMA (loads long in flight)
    f32x4 acc = {0.f, 0.f, 0.f, 0.f};
#pragma unroll
    for (int kc = 0; kc < 4; ++kc) {
      acc = __builtin_amdgcn_mfma_f32_16x16x32_bf16(xf[kc], wih_hi[kc], acc, 0, 0, 0);
      acc = __builtin_amdgcn_mfma_f32_16x16x32_bf16(xf[kc], wih_lo[kc], acc, 0, 0, 0);
    }

    // h-path: fragments from swizzled LDS; 3-term hi/lo MFMA
    {
      const int br = lane & 15;
      const unsigned sw = (unsigned)(br & 7) << 2;
      const unsigned rowb = (unsigned)br * 512;
#pragma unroll
      for (int kc = 0; kc < 4; ++kc) {
        unsigned j = (unsigned)(k0 + q * 8 + kc * 32);
        uint4 A  = *(const uint4*)&LhexF[rowb + (j ^ sw)];
        uint4 Bv = *(const uint4*)&LhexF[rowb + ((j + 4) ^ sw)];
        unsigned pw[8] = {A.x, A.y, A.z, A.w, Bv.x, Bv.y, Bv.z, Bv.w};
        bf16x8 hh, hl;
#pragma unroll
        for (int r = 0; r < 8; ++r) {
          hh[r] = (short)(pw[r] & 0xffffu);
          hl[r] = (short)(pw[r] >> 16);
        }
        acc = __builtin_amdgcn_mfma_f32_16x16x32_bf16(hh, whh_hi[kc], acc, 0, 0, 0);
        acc = __builtin_amdgcn_mfma_f32_16x16x32_bf16(hl, whh_hi[kc], acc, 0, 0, 0);
        acc = __builtin_amdgcn_mfma_f32_16x16x32_bf16(hh, whh_lo[kc], acc, 0, 0, 0);
      }
    }

    if (kw != 0) {
      const int slot = kw - 1 + half * 3;
#pragma unroll
      for (int r = 0; r < 4; ++r) part[slot][r][lane] = acc[r];
    }
    __syncthreads();  // S2
    // WAR safety: reducers read part between S2(t) and S1(t+1); writers'
    // next part-write is after S1(t+1), which requires reducers to arrive.

    if (kw == 0) {  // reducer waves 0 (half 0) and 4 (half 1)
      const int s0 = half * 3;
      float g[4];
#pragma unroll
      for (int r = 0; r < 4; ++r) {
        g[r] = acc[r] + part[s0][r][lane] + part[s0 + 1][r][lane] + part[s0 + 2][r][lane] + biasr;
        gl[half][q * 4 + r][c] = g[r];  // D layout: row=(lane>>4)*4+r, col=lane&15
      }
      // same-wave LDS RAW: compiler inserts lgkmcnt waits
      int bb = lane & 15;
      float gi = gl[half][bb][j2];
      float gf = gl[half][bb][4 + j2];
      float gg = gl[half][bb][8 + j2];
      float go = gl[half][bb][12 + j2];
      float cn = sigm(gf) * cst + sigm(gi) * tanh_f(gg);
      cst = cn;
      float hv = sigm(go) * tanh_f(cn);

      // publish h (critical path): sc1 write-through to MALL, ack, then flag
      unsigned short ha = f2bf(hv), la = f2bf(hv - bf2f(ha));
      unsigned int* dst = hex + (size_t)((t + 1) & 1) * (NB * NH) + (size_t)eb * NH;
      __hip_atomic_store(dst + jg, (unsigned)ha | ((unsigned)la << 16),
                         __ATOMIC_RELAXED, __HIP_MEMORY_SCOPE_AGENT);
      asm volatile("s_waitcnt vmcnt(0)" ::: "memory");  // hex store at MALL
      if (lane == 0)
        __hip_atomic_store(flags + n * 2 + half, (unsigned)(t + 2),
                           __ATOMIC_RELAXED, __HIP_MEMORY_SCOPE_AGENT);

      // deferred, non-critical stores (normal cached path)
      out[((size_t)eb * NS + t) * NH + jg] = hv;
      if (t == NS - 1) {
        size_t hoff = (size_t)NB * NS * NH;
        out[hoff + (size_t)eb * NH + jg] = hv;
        out[hoff + (size_t)NB * NH + (size_t)eb * NH + jg] = cn;
      }
    }
  }
}

extern "C" void kernel_launch(void* const* d_in, const int* in_sizes, int n_in,
                              void* d_out, int out_size, void* d_ws, size_t ws_size,
                              hipStream_t stream) {
  if (ws_size < WS_BYTES_NEEDED) return;  // fail visibly (poisoned d_out) rather than corrupt

  const float* x   = (const float*)d_in[0];
  const float* h0  = (const float*)d_in[1];
  const float* c0  = (const float*)d_in[2];
  const float* Wih = (const float*)d_in[3];
  const float* bih = (const float*)d_in[4];
  const float* Whh = (const float*)d_in[5];
  const float* bhh = (const float*)d_in[6];
  float* out = (float*)d_out;
  unsigned int* ws = (unsigned int*)d_ws;
  unsigned short* xbptr = (unsigned short*)(ws + XBF_OFF);

  k_xconv<<<dim3(16384), dim3(256), 0, stream>>>(x, xbptr);
  k_init<<<dim3(128), dim3(256), 0, stream>>>(h0, ws);

  void* args[] = {(void*)&Wih, (void*)&bih, (void*)&Whh, (void*)&bhh,
                  (void*)&c0,  (void*)&out, (void*)&ws};
  hipLaunchCooperativeKernel((const void*)k_lstm, dim3(256), dim3(512), args, 0, stream);
}

// Round 5
// 3477.192 us; speedup vs baseline: 1.5629x; 1.5629x over previous
//
#include <hip/hip_runtime.h>
#include <stdint.h>

#define NB 64
#define NS 512
#define NI 512
#define NH 512

typedef __attribute__((ext_vector_type(8))) short bf16x8;
typedef __attribute__((ext_vector_type(4))) float f32x4;

__device__ __forceinline__ unsigned short f2bf(float f) {
  unsigned u = __float_as_uint(f);
  return (unsigned short)((u + 0x7fffu + ((u >> 16) & 1u)) >> 16);
}
__device__ __forceinline__ float bf2f(unsigned short h) {
  return __uint_as_float(((unsigned)h) << 16);
}
__device__ __forceinline__ float sigm(float x) { return 1.0f / (1.0f + __expf(-x)); }
__device__ __forceinline__ float tanh_f(float x) {
  float e = __expf(-2.0f * fabsf(x));
  return copysignf((1.0f - e) / (1.0f + e), x);
}
__device__ __forceinline__ unsigned long long ald64(const unsigned long long* p) {
  return __hip_atomic_load(p, __ATOMIC_RELAXED, __HIP_MEMORY_SCOPE_AGENT);
}

// ws layout (u32 units):
//  [0,512):              flags[4 m-groups][128], idx = n*2 + tile; monotonic step counters
//  [1024, 1024+65536):   h_ex[2 bufs][64 b][512 j]  (packed bf16 hi | lo<<16)
//  [66560, +8388608):    x_bf16 as u16[64][512][512]
#define FLAGS_OFF 0
#define HEX_OFF 1024
#define XBF_OFF 66560
#define WS_BYTES_NEEDED (XBF_OFF * 4 + (size_t)NB * NS * NI * 2)

__global__ __launch_bounds__(256) void k_xconv(const float* __restrict__ x,
                                               unsigned short* __restrict__ xb) {
  size_t i = ((size_t)blockIdx.x * 256 + threadIdx.x) * 4;
  float4 v = *(const float4*)(x + i);
  ushort4 o;
  o.x = f2bf(v.x); o.y = f2bf(v.y); o.z = f2bf(v.z); o.w = f2bf(v.w);
  *(ushort4*)(xb + i) = o;
}

__global__ __launch_bounds__(256) void k_init(const float* __restrict__ h0,
                                              unsigned int* __restrict__ ws) {
  int idx = blockIdx.x * 256 + threadIdx.x;
  if (idx < NB * NH) {
    float v = h0[idx];
    unsigned short hi = f2bf(v);
    unsigned short lo = f2bf(v - bf2f(hi));
    ws[HEX_OFF + idx] = (unsigned)hi | ((unsigned)lo << 16);
  }
  if (idx < 512) ws[FLAGS_OFF + idx] = 1u;  // h version 0 available
}

// Persistent cooperative LSTM kernel.
// grid 256 WGs x 512 thr. WG: m=bid&3 (16 batches), n=bid>>2 (8 h-cols -> 32 gate rows).
// wave w = K-eighth (64 K-cols); every wave computes BOTH 16-gate-row tiles (u=0,1).
// h exchange: producers sc1-store h (hi|lo packed) to MALL + vmcnt ack + flag;
// wave 7 polls 128 flags; after S1 every wave batch-issues 8 independent u64
// sc1 loads of its own h fragment (ONE MALL round trip, no LDS staging, no
// fences, L1/L2 never invalidated). Reducer waves 0/1 handle tile 0/1 epilogue.
__global__ __launch_bounds__(512, 2) void k_lstm(
    const float* __restrict__ Wih, const float* __restrict__ bih,
    const float* __restrict__ Whh, const float* __restrict__ bhh,
    const float* __restrict__ c0, float* __restrict__ out,
    unsigned int* __restrict__ ws) {
  const int tid = threadIdx.x;
  const int lane = tid & 63;
  const int w = tid >> 6;   // K-eighth
  const int k0 = w * 64;
  const int m = blockIdx.x & 3;
  const int n = blockIdx.x >> 2;

  unsigned int* flags = ws + FLAGS_OFF + m * 128;
  unsigned int* hex = ws + HEX_OFF;
  const unsigned short* xb = (const unsigned short*)(ws + XBF_OFF);

  // B-fragment lane mapping: col=lane&15, k=(lane>>4)*8+r
  const int c = lane & 15;
  const int q = lane >> 4;
  const int jj = c & 3;
  const int gate = c >> 2;

  // ---- weight fragments (hi/lo bf16 split), 2 tiles x 2 K-chunks ----
  bf16x8 whh_hi[2][2], whh_lo[2][2], wih_hi[2][2], wih_lo[2][2];
  float biasr[2];
#pragma unroll
  for (int u = 0; u < 2; ++u) {
    const int wrow = gate * NH + n * 8 + u * 4 + jj;
#pragma unroll
    for (int kc = 0; kc < 2; ++kc) {
      const int kb = k0 + kc * 32 + q * 8;
      const float* ph = Whh + (size_t)wrow * NH + kb;
      const float* pi = Wih + (size_t)wrow * NI + kb;
      float4 a0 = *(const float4*)ph, a1 = *(const float4*)(ph + 4);
      float4 b0 = *(const float4*)pi, b1 = *(const float4*)(pi + 4);
      float vh[8] = {a0.x, a0.y, a0.z, a0.w, a1.x, a1.y, a1.z, a1.w};
      float vi[8] = {b0.x, b0.y, b0.z, b0.w, b1.x, b1.y, b1.z, b1.w};
#pragma unroll
      for (int r = 0; r < 8; ++r) {
        unsigned short h16 = f2bf(vh[r]);
        whh_hi[u][kc][r] = (short)h16;
        whh_lo[u][kc][r] = (short)f2bf(vh[r] - bf2f(h16));
        unsigned short i16 = f2bf(vi[r]);
        wih_hi[u][kc][r] = (short)i16;
        wih_lo[u][kc][r] = (short)f2bf(vi[r] - bf2f(i16));
      }
    }
    biasr[u] = bih[wrow] + bhh[wrow];
  }

  // epilogue state (reducer waves 0,1): lane = (b=lane&15, j2=lane>>4)
  const int eb = m * 16 + (lane & 15);
  const int j2 = lane >> 4;
  const int wu = w & 1;
  const int jg = n * 8 + wu * 4 + j2;
  float cst = c0[(size_t)eb * NH + jg];

  __shared__ float part[2][8][4][64];  // [tile][wave][reg][lane], lane-stride-1
  __shared__ float gl[2][16][17];

  const unsigned short* xbase = xb + (size_t)eb * NS * NI + k0 + q * 8;

  // preload x fragments for t=0
  bf16x8 xfa0 = *(const bf16x8*)(xbase);
  bf16x8 xfa1 = *(const bf16x8*)(xbase + 32);

  for (int t = 0; t < NS; ++t) {
    f32x4 acc0 = {0.f, 0.f, 0.f, 0.f};
    f32x4 acc1 = {0.f, 0.f, 0.f, 0.f};

    if (w == 7) {
      // poll all 128 half-flags (2 per lane as one u64)
      const unsigned tgt = (unsigned)(t + 1);
      const unsigned long long* fp = (const unsigned long long*)flags + lane;
      unsigned long long fl = ald64(fp);
      while (!__all((int)((unsigned)fl >= tgt && (unsigned)(fl >> 32) >= tgt)))
        fl = ald64(fp);
      asm volatile("" ::: "memory");  // keep hex loads below the poll
    } else {
      // x-path MFMA while poller spins (x loads long in flight)
      acc0 = __builtin_amdgcn_mfma_f32_16x16x32_bf16(xfa0, wih_hi[0][0], acc0, 0, 0, 0);
      acc0 = __builtin_amdgcn_mfma_f32_16x16x32_bf16(xfa0, wih_lo[0][0], acc0, 0, 0, 0);
      acc1 = __builtin_amdgcn_mfma_f32_16x16x32_bf16(xfa0, wih_hi[1][0], acc1, 0, 0, 0);
      acc1 = __builtin_amdgcn_mfma_f32_16x16x32_bf16(xfa0, wih_lo[1][0], acc1, 0, 0, 0);
      acc0 = __builtin_amdgcn_mfma_f32_16x16x32_bf16(xfa1, wih_hi[0][1], acc0, 0, 0, 0);
      acc0 = __builtin_amdgcn_mfma_f32_16x16x32_bf16(xfa1, wih_lo[0][1], acc0, 0, 0, 0);
      acc1 = __builtin_amdgcn_mfma_f32_16x16x32_bf16(xfa1, wih_hi[1][1], acc1, 0, 0, 0);
      acc1 = __builtin_amdgcn_mfma_f32_16x16x32_bf16(xfa1, wih_lo[1][1], acc1, 0, 0, 0);
    }
    __syncthreads();  // S1: h version t published (poller verified)

    // batch-issue this wave's h fragment: 8 independent u64 sc1 loads, 1 round trip
    const unsigned long long* hr =
        (const unsigned long long*)(hex + (size_t)(t & 1) * (NB * NH)) +
        (((size_t)eb * NH + k0 + q * 8) >> 1);
    unsigned long long h0 = ald64(hr + 0);
    unsigned long long h1 = ald64(hr + 1);
    unsigned long long h2 = ald64(hr + 2);
    unsigned long long h3 = ald64(hr + 3);
    unsigned long long h4 = ald64(hr + 16);
    unsigned long long h5 = ald64(hr + 17);
    unsigned long long h6 = ald64(hr + 18);
    unsigned long long h7 = ald64(hr + 19);

    // writer waves: prefetch next x now (in flight across epilogue)
    const int tn = (t + 1 < NS) ? t + 1 : t;
    bf16x8 xfn0, xfn1;
    if (w >= 2) {
      const unsigned short* xrn = xbase + (size_t)tn * NI;
      xfn0 = *(const bf16x8*)(xrn);
      xfn1 = *(const bf16x8*)(xrn + 32);
    }

    if (w == 7) {  // poller runs its x-path now
      acc0 = __builtin_amdgcn_mfma_f32_16x16x32_bf16(xfa0, wih_hi[0][0], acc0, 0, 0, 0);
      acc0 = __builtin_amdgcn_mfma_f32_16x16x32_bf16(xfa0, wih_lo[0][0], acc0, 0, 0, 0);
      acc1 = __builtin_amdgcn_mfma_f32_16x16x32_bf16(xfa0, wih_hi[1][0], acc1, 0, 0, 0);
      acc1 = __builtin_amdgcn_mfma_f32_16x16x32_bf16(xfa0, wih_lo[1][0], acc1, 0, 0, 0);
      acc0 = __builtin_amdgcn_mfma_f32_16x16x32_bf16(xfa1, wih_hi[0][1], acc0, 0, 0, 0);
      acc0 = __builtin_amdgcn_mfma_f32_16x16x32_bf16(xfa1, wih_lo[0][1], acc0, 0, 0, 0);
      acc1 = __builtin_amdgcn_mfma_f32_16x16x32_bf16(xfa1, wih_hi[1][1], acc1, 0, 0, 0);
      acc1 = __builtin_amdgcn_mfma_f32_16x16x32_bf16(xfa1, wih_lo[1][1], acc1, 0, 0, 0);
    }

    // h-path MFMA, K-chunk 0
    {
      unsigned pw[8] = {(unsigned)h0, (unsigned)(h0 >> 32), (unsigned)h1, (unsigned)(h1 >> 32),
                        (unsigned)h2, (unsigned)(h2 >> 32), (unsigned)h3, (unsigned)(h3 >> 32)};
      bf16x8 hh, hl;
#pragma unroll
      for (int r = 0; r < 8; ++r) {
        hh[r] = (short)(pw[r] & 0xffffu);
        hl[r] = (short)(pw[r] >> 16);
      }
      acc0 = __builtin_amdgcn_mfma_f32_16x16x32_bf16(hh, whh_hi[0][0], acc0, 0, 0, 0);
      acc0 = __builtin_amdgcn_mfma_f32_16x16x32_bf16(hl, whh_hi[0][0], acc0, 0, 0, 0);
      acc0 = __builtin_amdgcn_mfma_f32_16x16x32_bf16(hh, whh_lo[0][0], acc0, 0, 0, 0);
      acc1 = __builtin_amdgcn_mfma_f32_16x16x32_bf16(hh, whh_hi[1][0], acc1, 0, 0, 0);
      acc1 = __builtin_amdgcn_mfma_f32_16x16x32_bf16(hl, whh_hi[1][0], acc1, 0, 0, 0);
      acc1 = __builtin_amdgcn_mfma_f32_16x16x32_bf16(hh, whh_lo[1][0], acc1, 0, 0, 0);
    }
    // h-path MFMA, K-chunk 1
    {
      unsigned pw[8] = {(unsigned)h4, (unsigned)(h4 >> 32), (unsigned)h5, (unsigned)(h5 >> 32),
                        (unsigned)h6, (unsigned)(h6 >> 32), (unsigned)h7, (unsigned)(h7 >> 32)};
      bf16x8 hh, hl;
#pragma unroll
      for (int r = 0; r < 8; ++r) {
        hh[r] = (short)(pw[r] & 0xffffu);
        hl[r] = (short)(pw[r] >> 16);
      }
      acc0 = __builtin_amdgcn_mfma_f32_16x16x32_bf16(hh, whh_hi[0][1], acc0, 0, 0, 0);
      acc0 = __builtin_amdgcn_mfma_f32_16x16x32_bf16(hl, whh_hi[0][1], acc0, 0, 0, 0);
      acc0 = __builtin_amdgcn_mfma_f32_16x16x32_bf16(hh, whh_lo[0][1], acc0, 0, 0, 0);
      acc1 = __builtin_amdgcn_mfma_f32_16x16x32_bf16(hh, whh_hi[1][1], acc1, 0, 0, 0);
      acc1 = __builtin_amdgcn_mfma_f32_16x16x32_bf16(hl, whh_hi[1][1], acc1, 0, 0, 0);
      acc1 = __builtin_amdgcn_mfma_f32_16x16x32_bf16(hh, whh_lo[1][1], acc1, 0, 0, 0);
    }

#pragma unroll
    for (int r = 0; r < 4; ++r) {
      part[0][w][r][lane] = acc0[r];
      part[1][w][r][lane] = acc1[r];
    }
    __syncthreads();  // S2
    // part WAR safety: next-step part writes happen only after S1(t+1), which
    // the reducers must also reach — i.e., after they finish reading part.

    if (w < 2) {  // reducer wave w handles tile u=w (gate rows n*8+w*4 .. +4 per gate)
      float g[4];
#pragma unroll
      for (int r = 0; r < 4; ++r) {
        float s = biasr[w];
#pragma unroll
        for (int ww = 0; ww < 8; ++ww) s += part[w][ww][r][lane];
        g[r] = s;
        gl[w][q * 4 + r][c] = g[r];  // D layout: row(batch)=(lane>>4)*4+r, col=lane&15
      }
      // same-wave LDS RAW: compiler inserts lgkmcnt waits
      const int bb = lane & 15;
      float gi = gl[w][bb][j2];
      float gf = gl[w][bb][4 + j2];
      float gg = gl[w][bb][8 + j2];
      float go = gl[w][bb][12 + j2];
      float cn = sigm(gf) * cst + sigm(gi) * tanh_f(gg);
      cst = cn;
      float hv = sigm(go) * tanh_f(cn);

      // publish h (critical path): sc1 write-through to MALL, ack, then flag
      unsigned short ha = f2bf(hv), la = f2bf(hv - bf2f(ha));
      unsigned int* dst = hex + (size_t)((t + 1) & 1) * (NB * NH) + (size_t)eb * NH;
      __hip_atomic_store(dst + jg, (unsigned)ha | ((unsigned)la << 16),
                         __ATOMIC_RELAXED, __HIP_MEMORY_SCOPE_AGENT);
      asm volatile("s_waitcnt vmcnt(0)" ::: "memory");  // only the hex store is outstanding
      if (lane == 0)
        __hip_atomic_store(flags + n * 2 + w, (unsigned)(t + 2),
                           __ATOMIC_RELAXED, __HIP_MEMORY_SCOPE_AGENT);

      // deferred, non-critical stores (normal cached path)
      out[((size_t)eb * NS + t) * NH + jg] = hv;
      if (t == NS - 1) {
        size_t hoff = (size_t)NB * NS * NH;
        out[hoff + (size_t)eb * NH + jg] = hv;
        out[hoff + (size_t)NB * NH + (size_t)eb * NH + jg] = cn;
      }

      // reducer prefetches next x only now (so vmcnt(0) above saw only hex store)
      const unsigned short* xrn = xbase + (size_t)tn * NI;
      xfn0 = *(const bf16x8*)(xrn);
      xfn1 = *(const bf16x8*)(xrn + 32);
    }

    xfa0 = xfn0;
    xfa1 = xfn1;
  }
}

extern "C" void kernel_launch(void* const* d_in, const int* in_sizes, int n_in,
                              void* d_out, int out_size, void* d_ws, size_t ws_size,
                              hipStream_t stream) {
  if (ws_size < WS_BYTES_NEEDED) return;  // fail visibly (poisoned d_out) rather than corrupt

  const float* x   = (const float*)d_in[0];
  const float* h0  = (const float*)d_in[1];
  const float* c0  = (const float*)d_in[2];
  const float* Wih = (const float*)d_in[3];
  const float* bih = (const float*)d_in[4];
  const float* Whh = (const float*)d_in[5];
  const float* bhh = (const float*)d_in[6];
  float* out = (float*)d_out;
  unsigned int* ws = (unsigned int*)d_ws;
  unsigned short* xbptr = (unsigned short*)(ws + XBF_OFF);

  k_xconv<<<dim3(16384), dim3(256), 0, stream>>>(x, xbptr);
  k_init<<<dim3(128), dim3(256), 0, stream>>>(h0, ws);

  void* args[] = {(void*)&Wih, (void*)&bih, (void*)&Whh, (void*)&bhh,
                  (void*)&c0,  (void*)&out, (void*)&ws};
  hipLaunchCooperativeKernel((const void*)k_lstm, dim3(256), dim3(512), args, 0, stream);
}